// Round 18
// baseline (91.706 us; speedup 1.0000x reference)
//
#include <hip/hip_runtime.h>
#include <hip/hip_bf16.h>

#define NB 4096
#define ND 512

typedef int i32x4 __attribute__((ext_vector_type(4)));
typedef int i32x8 __attribute__((ext_vector_type(8)));
typedef float f32x4 __attribute__((ext_vector_type(4)));

#define AS1 __attribute__((address_space(1)))
#define AS3 __attribute__((address_space(3)))

// raw v_exp_f32: D = 2^S0 (pure ALU, register-dep ordered)
__device__ __forceinline__ float fexp2(float x) {
    float r;
    asm("v_exp_f32 %0, %1" : "=v"(r) : "v"(x));
    return r;
}

// ---- f32 -> fp8 e4m3fn (OCP), RNE, |x| <= 1 ----
__device__ __forceinline__ unsigned int f2e4m3(float x) {
    float a = fabsf(x);
    unsigned s = (__float_as_uint(x) >> 24) & 0x80u;
    if (a < 0.015625f) {                       // denorm/zero: step 2^-9
        int q = __float2int_rn(a * 512.0f);
        return s | (unsigned)q;
    }
    unsigned u = __float_as_uint(a);
    u += 0x7FFFFu + ((u >> 20) & 1u);          // RNE to 3-bit mantissa
    unsigned e8 = (u >> 23) - 120u;
    unsigned m = (u >> 20) & 7u;
    return s | (e8 << 3) | m;
}

// ---------------- normalize + cast to fp8 (wave per row) + zero-init sums ----------------
__global__ __launch_bounds__(256) void nrm_kernel(
    const float* __restrict__ z0, const float* __restrict__ z1,
    const float* __restrict__ z2, unsigned char* __restrict__ nrm8,
    float* __restrict__ rowsum, float* __restrict__ colsum)
{
    const int w = threadIdx.x >> 6, lane = threadIdx.x & 63;
    const int row = blockIdx.x * 4 + w;
    const int p = blockIdx.y;
    if (lane == 0) {
        rowsum[p * NB + row] = 0.f;
        colsum[p * NB + row] = 0.f;
    }
    const float* z = (p == 0) ? z0 : (p == 1) ? z1 : z2;
    const float4* zr = (const float4*)(z + (size_t)row * ND);
    const float4 a = zr[lane * 2], b = zr[lane * 2 + 1];
    float ss = a.x * a.x + a.y * a.y + a.z * a.z + a.w * a.w
             + b.x * b.x + b.y * b.y + b.z * b.z + b.w * b.w;
    #pragma unroll
    for (int m = 32; m >= 1; m >>= 1) ss += __shfl_xor(ss, m);
    const float inv = 1.0f / fmaxf(sqrtf(ss), 1e-8f);
    uint2 o;
    o.x = f2e4m3(a.x * inv) | (f2e4m3(a.y * inv) << 8)
        | (f2e4m3(a.z * inv) << 16) | (f2e4m3(a.w * inv) << 24);
    o.y = f2e4m3(b.x * inv) | (f2e4m3(b.y * inv) << 8)
        | (f2e4m3(b.z * inv) << 16) | (f2e4m3(b.w * inv) << 24);
    *(uint2*)(nrm8 + ((size_t)p * NB + row) * ND + lane * 8) = o;
}

// ---------------- fused pair GEMM, MX-fp8: 128 rows x 512 cols per block ----------------
// LDS-traffic-halved variant of the champion: A fragments load DIRECTLY from
// global (L2-resident 64 KB panel; 16 cache lines/instr coalescing), only B is
// staged through LDS (2 x 16 KB double-buffer -> 3 blocks/CU co-resident).
// One barrier + counted vmcnt gate per stage. B maps/swizzle proven r6-r16.
__global__ __launch_bounds__(256, 3) void pair_gemm_kernel(
    const unsigned char* __restrict__ nrm8,
    float* __restrict__ rowsum, float* __restrict__ colsum,
    float* __restrict__ diag)
{
    // 768 blocks: bxc = bid&7 (one 512-col B chunk per XCD, L2-resident);
    // r = bid>>3: p = r>>5 (0..2), by = r&31.
    const int bid = blockIdx.x;
    const int bxc = bid & 7;
    const int r = bid >> 3;
    const int p = r >> 5;
    const int by = r & 31;
    const int ia = (p == 2) ? 1 : 0;
    const int ib = (p == 0) ? 1 : 2;

    const char* Ag = (const char*)nrm8 + ((size_t)ia * NB + (size_t)by * 128) * ND;
    const char* Bg = (const char*)nrm8 + ((size_t)ib * NB + (size_t)bxc * 512) * ND;

    __shared__ char lds[32768];  // B bufs at 0, 16384

    const int tid = threadIdx.x;
    const int lane = tid & 63;
    const int w = tid >> 6;
    const int wr = w >> 1, wc = w & 1;   // 2x2 wave grid; wave tile 64x64
    const int lr = lane & 15, lg = lane >> 4;

    // B staging map (proven): chunk c = q*256+tid -> LDS linear c*16; source
    // row rr = c>>3, phys slot qp = c&7 holds logical qp^(rr&7) (rule 21).
    int srcOff[4];
    #pragma unroll
    for (int q = 0; q < 4; ++q) {
        const int c = q * 256 + tid;
        const int rr = c >> 3;
        srcOff[q] = rr * ND + (((c & 7) ^ (rr & 7)) * 16);
    }

    // B frag reads (proven): logical slots {2lg, 2lg+1}, phys = ^(lr&7).
    const int s0 = ((2 * lg) ^ (lr & 7)) * 16;
    const int s1 = ((2 * lg + 1) ^ (lr & 7)) * 16;
    int brow[4];
    #pragma unroll
    for (int n = 0; n < 4; ++n) brow[n] = (wc * 64 + n * 16 + lr) * 128;

    // A direct-load row bases: row = wr*64 + m*16 + lr, k bytes lg*32..+32
    // (same logical k-map as B -> HW-internal k permutation cancels in A.B^T)
    const char* pa[4];
    #pragma unroll
    for (int m = 0; m < 4; ++m)
        pa[m] = Ag + (size_t)(wr * 64 + m * 16 + lr) * ND + lg * 32;

    f32x4 acc[4][4] = {};
    float rs[4][4];
    #pragma unroll
    for (int m = 0; m < 4; ++m)
        #pragma unroll
        for (int j = 0; j < 4; ++j) rs[m][j] = 0.f;

    #define STAGE(gsrc, dstbase) do {                                               \
        _Pragma("unroll")                                                           \
        for (int q = 0; q < 4; ++q)                                                 \
            __builtin_amdgcn_global_load_lds(                                       \
                (const AS1 void*)((gsrc) + srcOff[q]),                              \
                (AS3 void*)(lds + (dstbase) + q * 4096 + tid * 16), 16, 0, 0);      \
    } while (0)

    #define LDF(dst, base) do {                                                     \
        i32x4 lo_ = *(const i32x4*)((base) + s0);                                   \
        i32x4 hi_ = *(const i32x4*)((base) + s1);                                   \
        dst = __builtin_shufflevector(lo_, hi_, 0, 1, 2, 3, 4, 5, 6, 7);            \
    } while (0)

    #define SC 0x7F7F7F7F
    constexpr float C10 = 14.42695040888963f;

    // prologue: B(0) -> buf0
    STAGE(Bg, 0);
    asm volatile("s_waitcnt vmcnt(0)" ::: "memory");
    __builtin_amdgcn_s_barrier();

    #pragma unroll 1
    for (int s = 0; s < 16; ++s) {
        const int bxl = s >> 2, k = s & 3;
        const int pb = s & 1;

        // A fragments for stage s: direct from global (L2 hit; compiler
        // inserts the counted vmcnt before the MFMA uses)
        i32x8 af[4];
        #pragma unroll
        for (int m = 0; m < 4; ++m) {
            i32x4 lo = *(const i32x4*)(pa[m] + k * 128);
            i32x4 hi = *(const i32x4*)(pa[m] + k * 128 + 16);
            af[m] = __builtin_shufflevector(lo, hi, 0, 1, 2, 3, 4, 5, 6, 7);
        }

        // stage B(s+1) into the other buffer (last read at stage s-1, same
        // parity -> protected by the end-of-(s-1) barrier)
        if (s < 15) {
            const int s1i = s + 1;
            STAGE(Bg + (size_t)(s1i >> 2) * 128 * ND + (s1i & 3) * 128,
                  ((s1i & 1) * 16384));
        }

        // B fragments for stage s from LDS
        const char* bb = lds + pb * 16384;
        i32x8 bf[4];
        #pragma unroll
        for (int n = 0; n < 4; ++n) LDF(bf[n], bb + brow[n]);

        __builtin_amdgcn_s_setprio(1);
        #pragma unroll
        for (int m = 0; m < 4; ++m)
            #pragma unroll
            for (int n = 0; n < 4; ++n)
                acc[m][n] = __builtin_amdgcn_mfma_scale_f32_16x16x128_f8f6f4(
                    af[m], bf[n], acc[m][n], 0, 0, 0, SC, 0, SC);
        __builtin_amdgcn_s_setprio(0);

        // per-bx-tile epilogue (k==3): overlaps the in-flight B DMA
        if (k == 3) {
            const int bxg = bxc * 4 + bxl;
            if (by == bxg && wr == wc) {
                #pragma unroll
                for (int m = 0; m < 4; ++m)
                    #pragma unroll
                    for (int j = 0; j < 4; ++j)
                        if (lr == lg * 4 + j)
                            diag[p * NB + by * 128 + wr * 64 + m * 16 + lr] = acc[m][m][j];
            }
            float cs[4] = {0.f, 0.f, 0.f, 0.f};
            #pragma unroll
            for (int m = 0; m < 4; ++m)
                #pragma unroll
                for (int n = 0; n < 4; ++n)
                    #pragma unroll
                    for (int j = 0; j < 4; ++j) {
                        float e = fexp2(fmaf(acc[m][n][j], C10, -C10));
                        rs[m][j] += e;
                        cs[n] += e;
                    }
            #pragma unroll
            for (int n = 0; n < 4; ++n) {
                float v = cs[n];
                v += __shfl_xor(v, 16);
                v += __shfl_xor(v, 32);
                if (lg == 0)
                    atomicAdd(&colsum[p * NB + bxg * 128 + wc * 64 + n * 16 + lr], v);
            }
            #pragma unroll
            for (int m = 0; m < 4; ++m)
                #pragma unroll
                for (int n = 0; n < 4; ++n)
                    acc[m][n] = (f32x4){0.f, 0.f, 0.f, 0.f};
        }

        // gate: B(s+1) DMA landed. A loads were drained before the MFMAs.
        // k==3: the 4 colsum atomics are the newest vmem ops -> vmcnt(4).
        if (s < 15) {
            if (k == 3) asm volatile("s_waitcnt vmcnt(4)" ::: "memory");
            else        asm volatile("s_waitcnt vmcnt(0)" ::: "memory");
            __builtin_amdgcn_s_barrier();
        }
    }
    #undef STAGE
    #undef LDF

    // ---- final rowsum flush (accumulated over all 4 bx tiles) ----
    #pragma unroll
    for (int m = 0; m < 4; ++m)
        #pragma unroll
        for (int j = 0; j < 4; ++j) {
            float v = rs[m][j];
            v += __shfl_xor(v, 1);
            v += __shfl_xor(v, 2);
            v += __shfl_xor(v, 4);
            v += __shfl_xor(v, 8);
            if (lr == 0)
                atomicAdd(&rowsum[p * NB + by * 128 + wr * 64 + m * 16 + lg * 4 + j], v);
        }
}

// ---------------- final reduce: 48 blocks, atomic accumulate ----------------
__global__ __launch_bounds__(256) void finalize_kernel(
    const float* __restrict__ rowsum, const float* __restrict__ colsum,
    const float* __restrict__ diag, float* __restrict__ out)
{
    const int i = blockIdx.x * 256 + threadIdx.x;   // 48*256 = 12288 exactly
    float s = 0.5f * (logf(rowsum[i]) + logf(colsum[i])) + 10.0f - 10.0f * diag[i];
    #pragma unroll
    for (int m = 32; m >= 1; m >>= 1) s += __shfl_xor(s, m);
    __shared__ float sw[4];
    if ((threadIdx.x & 63) == 0) sw[threadIdx.x >> 6] = s;
    __syncthreads();
    if (threadIdx.x == 0)
        atomicAdd(out, (sw[0] + sw[1] + sw[2] + sw[3]) * (1.0f / (3.0f * NB)));
}

extern "C" void kernel_launch(void* const* d_in, const int* in_sizes, int n_in,
                              void* d_out, int out_size, void* d_ws, size_t ws_size,
                              hipStream_t stream) {
    const float* z0 = (const float*)d_in[0];
    const float* z1 = (const float*)d_in[1];
    const float* z2 = (const float*)d_in[2];
    float* out = (float*)d_out;

    char* ws = (char*)d_ws;
    unsigned char* nrm8 = (unsigned char*)ws;               // 3*4096*512 fp8 = 6.3 MB
    const size_t nrm_bytes = (size_t)3 * NB * ND;
    float* rowsum = (float*)(ws + nrm_bytes);               // 3*4096 f32
    float* colsum = rowsum + 3 * NB;                        // 3*4096 f32
    float* diag = colsum + 3 * NB;                          // 3*4096 f32 (fully overwritten)

    hipMemsetAsync(out, 0, sizeof(float), stream);
    nrm_kernel<<<dim3(NB / 4, 3), 256, 0, stream>>>(z0, z1, z2, nrm8, rowsum, colsum);
    pair_gemm_kernel<<<768, 256, 0, stream>>>(nrm8, rowsum, colsum, diag);
    finalize_kernel<<<48, 256, 0, stream>>>(rowsum, colsum, diag, out);
}

// Round 19
// 61.821 us; speedup vs baseline: 1.4834x; 1.4834x over previous
//
#include <hip/hip_runtime.h>
#include <hip/hip_bf16.h>

#define NB 4096
#define ND 512

typedef int i32x4 __attribute__((ext_vector_type(4)));
typedef int i32x8 __attribute__((ext_vector_type(8)));
typedef float f32x4 __attribute__((ext_vector_type(4)));

#define AS1 __attribute__((address_space(1)))
#define AS3 __attribute__((address_space(3)))

// raw v_exp_f32: D = 2^S0 (pure ALU, register-dep ordered)
__device__ __forceinline__ float fexp2(float x) {
    float r;
    asm("v_exp_f32 %0, %1" : "=v"(r) : "v"(x));
    return r;
}

// ---- f32 -> fp8 e4m3fn (OCP), RNE, |x| <= 1 ----
__device__ __forceinline__ unsigned int f2e4m3(float x) {
    float a = fabsf(x);
    unsigned s = (__float_as_uint(x) >> 24) & 0x80u;
    if (a < 0.015625f) {                       // denorm/zero: step 2^-9
        int q = __float2int_rn(a * 512.0f);
        return s | (unsigned)q;
    }
    unsigned u = __float_as_uint(a);
    u += 0x7FFFFu + ((u >> 20) & 1u);          // RNE to 3-bit mantissa
    unsigned e8 = (u >> 23) - 120u;
    unsigned m = (u >> 20) & 7u;
    return s | (e8 << 3) | m;
}

// ---------------- normalize + cast to fp8 (wave per row) + zero-init sums ----------------
__global__ __launch_bounds__(256) void nrm_kernel(
    const float* __restrict__ z0, const float* __restrict__ z1,
    const float* __restrict__ z2, unsigned char* __restrict__ nrm8,
    float* __restrict__ rowsum, float* __restrict__ colsum)
{
    const int w = threadIdx.x >> 6, lane = threadIdx.x & 63;
    const int row = blockIdx.x * 4 + w;
    const int p = blockIdx.y;
    if (lane == 0) {
        rowsum[p * NB + row] = 0.f;
        colsum[p * NB + row] = 0.f;
    }
    const float* z = (p == 0) ? z0 : (p == 1) ? z1 : z2;
    const float4* zr = (const float4*)(z + (size_t)row * ND);
    const float4 a = zr[lane * 2], b = zr[lane * 2 + 1];
    float ss = a.x * a.x + a.y * a.y + a.z * a.z + a.w * a.w
             + b.x * b.x + b.y * b.y + b.z * b.z + b.w * b.w;
    #pragma unroll
    for (int m = 32; m >= 1; m >>= 1) ss += __shfl_xor(ss, m);
    const float inv = 1.0f / fmaxf(sqrtf(ss), 1e-8f);
    uint2 o;
    o.x = f2e4m3(a.x * inv) | (f2e4m3(a.y * inv) << 8)
        | (f2e4m3(a.z * inv) << 16) | (f2e4m3(a.w * inv) << 24);
    o.y = f2e4m3(b.x * inv) | (f2e4m3(b.y * inv) << 8)
        | (f2e4m3(b.z * inv) << 16) | (f2e4m3(b.w * inv) << 24);
    *(uint2*)(nrm8 + ((size_t)p * NB + row) * ND + lane * 8) = o;
}

// ---------------- fused pair GEMM, MX-fp8: 128 rows x 512 cols per block ----------------
// CHAMPION (measured 49.3 us GEMM / 62.2 us total, round 16):
// 16 stages = 4 bx-tiles x 4 k-steps; A+B staged via 64 KB double-buffer
// (2 blocks/CU); 2-deep counted-vmcnt pipeline: stage s does
// LDF(s) -> lgkm(0)+barrier -> STAGE(s+2) into the just-freed buffer ->
// MFMA (operands in regs) -> epilogue(k==3) -> vmcnt(8|12)+barrier
// (drains stage s+1 only; s+2's DMA stays in flight a full stage).
__global__ __launch_bounds__(256, 2) void pair_gemm_kernel(
    const unsigned char* __restrict__ nrm8,
    float* __restrict__ rowsum, float* __restrict__ colsum,
    float* __restrict__ diag)
{
    // 768 blocks: bxc = bid&7 (one 512-col B chunk per XCD, L2-resident);
    // r = bid>>3: p = r>>5 (0..2), by = r&31.
    const int bid = blockIdx.x;
    const int bxc = bid & 7;
    const int r = bid >> 3;
    const int p = r >> 5;
    const int by = r & 31;
    const int ia = (p == 2) ? 1 : 0;
    const int ib = (p == 0) ? 1 : 2;

    const char* Ag = (const char*)nrm8 + ((size_t)ia * NB + (size_t)by * 128) * ND;
    const char* Bg = (const char*)nrm8 + ((size_t)ib * NB + (size_t)bxc * 512) * ND;

    __shared__ char lds[65536];  // A bufs at 0,16384; B bufs at 32768,49152

    const int tid = threadIdx.x;
    const int lane = tid & 63;
    const int w = tid >> 6;
    const int wr = w >> 1, wc = w & 1;   // 2x2 wave grid; wave tile 64x64
    const int lr = lane & 15, lg = lane >> 4;

    // staging map (proven): chunk c = q*256+tid -> LDS linear c*16; source row
    // rr = c>>3, phys slot qp = c&7 holds logical qp^(rr&7) (rule 21).
    int srcOff[4];
    #pragma unroll
    for (int q = 0; q < 4; ++q) {
        const int c = q * 256 + tid;
        const int rr = c >> 3;
        srcOff[q] = rr * ND + (((c & 7) ^ (rr & 7)) * 16);
    }

    // frag reads (proven): logical slots {2lg, 2lg+1}, phys = ^(lr&7).
    const int s0 = ((2 * lg) ^ (lr & 7)) * 16;
    const int s1 = ((2 * lg + 1) ^ (lr & 7)) * 16;
    int arow[4], brow[4];
    #pragma unroll
    for (int m = 0; m < 4; ++m) {
        arow[m] = (wr * 64 + m * 16 + lr) * 128;
        brow[m] = (wc * 64 + m * 16 + lr) * 128;
    }

    f32x4 acc[4][4] = {};
    float rs[4][4];
    #pragma unroll
    for (int m = 0; m < 4; ++m)
        #pragma unroll
        for (int j = 0; j < 4; ++j) rs[m][j] = 0.f;

    #define STAGE(gsrc, dstbase) do {                                               \
        _Pragma("unroll")                                                           \
        for (int q = 0; q < 4; ++q)                                                 \
            __builtin_amdgcn_global_load_lds(                                       \
                (const AS1 void*)((gsrc) + srcOff[q]),                              \
                (AS3 void*)(lds + (dstbase) + q * 4096 + tid * 16), 16, 0, 0);      \
    } while (0)

    #define LDF(dst, base) do {                                                     \
        i32x4 lo_ = *(const i32x4*)((base) + s0);                                   \
        i32x4 hi_ = *(const i32x4*)((base) + s1);                                   \
        dst = __builtin_shufflevector(lo_, hi_, 0, 1, 2, 3, 4, 5, 6, 7);            \
    } while (0)

    #define SC 0x7F7F7F7F
    constexpr float C10 = 14.42695040888963f;

    // prologue: stage 0 -> buf0, stage 1 -> buf1; drain stage 0 only (8 newer)
    STAGE(Ag, 0);
    STAGE(Bg, 32768);
    STAGE(Ag + 128, 16384);
    STAGE(Bg + 128, 32768 + 16384);
    asm volatile("s_waitcnt vmcnt(8)" ::: "memory");
    __builtin_amdgcn_s_barrier();

    #pragma unroll 1
    for (int s = 0; s < 16; ++s) {
        const int bxl = s >> 2, k = s & 3;
        const int pb = s & 1;

        // fragments for stage s (into regs)
        const char* ab = lds + pb * 16384;
        const char* bb = lds + 32768 + pb * 16384;
        i32x8 af[4], bf[4];
        #pragma unroll
        for (int m = 0; m < 4; ++m) LDF(af[m], ab + arow[m]);
        #pragma unroll
        for (int n = 0; n < 4; ++n) LDF(bf[n], bb + brow[n]);

        // buf[pb] is dead once ALL waves' reads are done -> reuse for stage s+2
        if (s < 14) {
            asm volatile("s_waitcnt lgkmcnt(0)" ::: "memory");
            __builtin_amdgcn_s_barrier();
            const int s2 = s + 2;
            STAGE(Ag + (s2 & 3) * 128, pb * 16384);
            STAGE(Bg + (size_t)(s2 >> 2) * 128 * ND + (s2 & 3) * 128,
                  32768 + pb * 16384);
        }

        __builtin_amdgcn_s_setprio(1);
        #pragma unroll
        for (int m = 0; m < 4; ++m)
            #pragma unroll
            for (int n = 0; n < 4; ++n)
                acc[m][n] = __builtin_amdgcn_mfma_scale_f32_16x16x128_f8f6f4(
                    af[m], bf[n], acc[m][n], 0, 0, 0, SC, 0, SC);
        __builtin_amdgcn_s_setprio(0);

        // per-bx-tile epilogue (k==3): overlaps the in-flight DMA
        if (k == 3) {
            const int bxg = bxc * 4 + bxl;
            if (by == bxg && wr == wc) {
                #pragma unroll
                for (int m = 0; m < 4; ++m)
                    #pragma unroll
                    for (int j = 0; j < 4; ++j)
                        if (lr == lg * 4 + j)
                            diag[p * NB + by * 128 + wr * 64 + m * 16 + lr] = acc[m][m][j];
            }
            float cs[4] = {0.f, 0.f, 0.f, 0.f};
            #pragma unroll
            for (int m = 0; m < 4; ++m)
                #pragma unroll
                for (int n = 0; n < 4; ++n)
                    #pragma unroll
                    for (int j = 0; j < 4; ++j) {
                        float e = fexp2(fmaf(acc[m][n][j], C10, -C10));
                        rs[m][j] += e;
                        cs[n] += e;
                    }
            #pragma unroll
            for (int n = 0; n < 4; ++n) {
                float v = cs[n];
                v += __shfl_xor(v, 16);
                v += __shfl_xor(v, 32);
                if (lg == 0)
                    atomicAdd(&colsum[p * NB + bxg * 128 + wc * 64 + n * 16 + lr], v);
            }
            #pragma unroll
            for (int m = 0; m < 4; ++m)
                #pragma unroll
                for (int n = 0; n < 4; ++n)
                    acc[m][n] = (f32x4){0.f, 0.f, 0.f, 0.f};
        }

        // gate: stage s+1 landed; stage s+2's 8 loads stay in flight.
        // k==3 stages have 4 extra vmem ops (colsum atomics) newer than s+1.
        if (s < 14) {
            if (k == 3) asm volatile("s_waitcnt vmcnt(12)" ::: "memory");
            else        asm volatile("s_waitcnt vmcnt(8)" ::: "memory");
            __builtin_amdgcn_s_barrier();
        } else if (s == 14) {
            asm volatile("s_waitcnt vmcnt(0)" ::: "memory");
            __builtin_amdgcn_s_barrier();
        }
    }
    #undef STAGE
    #undef LDF

    // ---- final rowsum flush (accumulated over all 4 bx tiles) ----
    #pragma unroll
    for (int m = 0; m < 4; ++m)
        #pragma unroll
        for (int j = 0; j < 4; ++j) {
            float v = rs[m][j];
            v += __shfl_xor(v, 1);
            v += __shfl_xor(v, 2);
            v += __shfl_xor(v, 4);
            v += __shfl_xor(v, 8);
            if (lr == 0)
                atomicAdd(&rowsum[p * NB + by * 128 + wr * 64 + m * 16 + lg * 4 + j], v);
        }
}

// ---------------- final reduce: 48 blocks, atomic accumulate ----------------
__global__ __launch_bounds__(256) void finalize_kernel(
    const float* __restrict__ rowsum, const float* __restrict__ colsum,
    const float* __restrict__ diag, float* __restrict__ out)
{
    const int i = blockIdx.x * 256 + threadIdx.x;   // 48*256 = 12288 exactly
    float s = 0.5f * (logf(rowsum[i]) + logf(colsum[i])) + 10.0f - 10.0f * diag[i];
    #pragma unroll
    for (int m = 32; m >= 1; m >>= 1) s += __shfl_xor(s, m);
    __shared__ float sw[4];
    if ((threadIdx.x & 63) == 0) sw[threadIdx.x >> 6] = s;
    __syncthreads();
    if (threadIdx.x == 0)
        atomicAdd(out, (sw[0] + sw[1] + sw[2] + sw[3]) * (1.0f / (3.0f * NB)));
}

extern "C" void kernel_launch(void* const* d_in, const int* in_sizes, int n_in,
                              void* d_out, int out_size, void* d_ws, size_t ws_size,
                              hipStream_t stream) {
    const float* z0 = (const float*)d_in[0];
    const float* z1 = (const float*)d_in[1];
    const float* z2 = (const float*)d_in[2];
    float* out = (float*)d_out;

    char* ws = (char*)d_ws;
    unsigned char* nrm8 = (unsigned char*)ws;               // 3*4096*512 fp8 = 6.3 MB
    const size_t nrm_bytes = (size_t)3 * NB * ND;
    float* rowsum = (float*)(ws + nrm_bytes);               // 3*4096 f32
    float* colsum = rowsum + 3 * NB;                        // 3*4096 f32
    float* diag = colsum + 3 * NB;                          // 3*4096 f32 (fully overwritten)

    hipMemsetAsync(out, 0, sizeof(float), stream);
    nrm_kernel<<<dim3(NB / 4, 3), 256, 0, stream>>>(z0, z1, z2, nrm8, rowsum, colsum);
    pair_gemm_kernel<<<768, 256, 0, stream>>>(nrm8, rowsum, colsum, diag);
    finalize_kernel<<<48, 256, 0, stream>>>(rowsum, colsum, diag, out);
}

// Round 20
// 60.059 us; speedup vs baseline: 1.5269x; 1.0293x over previous
//
#include <hip/hip_runtime.h>
#include <hip/hip_bf16.h>

#define NB 4096
#define ND 512

typedef int i32x4 __attribute__((ext_vector_type(4)));
typedef int i32x8 __attribute__((ext_vector_type(8)));
typedef float f32x4 __attribute__((ext_vector_type(4)));

#define AS1 __attribute__((address_space(1)))
#define AS3 __attribute__((address_space(3)))

// raw v_exp_f32: D = 2^S0 (pure ALU, register-dep ordered)
__device__ __forceinline__ float fexp2(float x) {
    float r;
    asm("v_exp_f32 %0, %1" : "=v"(r) : "v"(x));
    return r;
}

// ---- f32 -> fp8 e4m3fn (OCP), RNE, |x| <= 1 ----
__device__ __forceinline__ unsigned int f2e4m3(float x) {
    float a = fabsf(x);
    unsigned s = (__float_as_uint(x) >> 24) & 0x80u;
    if (a < 0.015625f) {                       // denorm/zero: step 2^-9
        int q = __float2int_rn(a * 512.0f);
        return s | (unsigned)q;
    }
    unsigned u = __float_as_uint(a);
    u += 0x7FFFFu + ((u >> 20) & 1u);          // RNE to 3-bit mantissa
    unsigned e8 = (u >> 23) - 120u;
    unsigned m = (u >> 20) & 7u;
    return s | (e8 << 3) | m;
}

// ---------------- normalize + cast to fp8 (wave per row) + zero-init sums ----------------
__global__ __launch_bounds__(256) void nrm_kernel(
    const float* __restrict__ z0, const float* __restrict__ z1,
    const float* __restrict__ z2, unsigned char* __restrict__ nrm8,
    float* __restrict__ rowsum, float* __restrict__ colsum)
{
    const int w = threadIdx.x >> 6, lane = threadIdx.x & 63;
    const int row = blockIdx.x * 4 + w;
    const int p = blockIdx.y;
    if (lane == 0) {
        rowsum[p * NB + row] = 0.f;
        colsum[p * NB + row] = 0.f;
    }
    const float* z = (p == 0) ? z0 : (p == 1) ? z1 : z2;
    const float4* zr = (const float4*)(z + (size_t)row * ND);
    const float4 a = zr[lane * 2], b = zr[lane * 2 + 1];
    float ss = a.x * a.x + a.y * a.y + a.z * a.z + a.w * a.w
             + b.x * b.x + b.y * b.y + b.z * b.z + b.w * b.w;
    #pragma unroll
    for (int m = 32; m >= 1; m >>= 1) ss += __shfl_xor(ss, m);
    const float inv = 1.0f / fmaxf(sqrtf(ss), 1e-8f);
    uint2 o;
    o.x = f2e4m3(a.x * inv) | (f2e4m3(a.y * inv) << 8)
        | (f2e4m3(a.z * inv) << 16) | (f2e4m3(a.w * inv) << 24);
    o.y = f2e4m3(b.x * inv) | (f2e4m3(b.y * inv) << 8)
        | (f2e4m3(b.z * inv) << 16) | (f2e4m3(b.w * inv) << 24);
    *(uint2*)(nrm8 + ((size_t)p * NB + row) * ND + lane * 8) = o;
}

// unit U (0..3071) -> (p, by, bx) + panel base pointers
struct UnitInfo { const char* Ag; const char* Bg; int p, by, bx; };
__device__ __forceinline__ UnitInfo unit_info(const unsigned char* nrm8, int U) {
    UnitInfo t;
    t.p = U >> 10;
    const int rem = U & 1023;
    t.by = rem >> 5;
    t.bx = rem & 31;
    const int ia = (t.p == 2) ? 1 : 0;
    const int ib = (t.p == 0) ? 1 : 2;
    t.Ag = (const char*)nrm8 + ((size_t)ia * NB + (size_t)t.by * 128) * ND;
    t.Bg = (const char*)nrm8 + ((size_t)ib * NB + (size_t)t.bx * 128) * ND;
    return t;
}

// ---------------- fused pair GEMM, MX-fp8: tail-free 512-block mapping ----------------
// Champion inner machinery (r16: 2-deep counted-vmcnt, 64 KB A/B dbuf,
// 2 blocks/CU) with 512 blocks x 6 units (24 stages) so ALL blocks are
// co-resident for the entire kernel (768-block version idled ~25% of the
// machine in the dispatch tail). Unit = (p, by, bx) 128x128 output tile.
// Panel (p,by) may change once mid-block: rowsum flushes at that unit's
// k==3 (gate widens to vmcnt(28) there), final panel flushes post-loop.
__global__ __launch_bounds__(256, 2) void pair_gemm_kernel(
    const unsigned char* __restrict__ nrm8,
    float* __restrict__ rowsum, float* __restrict__ colsum,
    float* __restrict__ diag)
{
    const int bid = blockIdx.x;                      // 512 blocks
    const int base = (bid & 7) * 384 + (bid >> 3) * 6;  // first unit (XCD-chunked)

    __shared__ char lds[65536];  // A bufs at 0,16384; B bufs at 32768,49152

    const int tid = threadIdx.x;
    const int lane = tid & 63;
    const int w = tid >> 6;
    const int wr = w >> 1, wc = w & 1;   // 2x2 wave grid; wave tile 64x64
    const int lr = lane & 15, lg = lane >> 4;

    // staging map (proven): chunk c = q*256+tid -> LDS linear c*16; source row
    // rr = c>>3, phys slot qp = c&7 holds logical qp^(rr&7) (rule 21).
    int srcOff[4];
    #pragma unroll
    for (int q = 0; q < 4; ++q) {
        const int c = q * 256 + tid;
        const int rr = c >> 3;
        srcOff[q] = rr * ND + (((c & 7) ^ (rr & 7)) * 16);
    }

    // frag reads (proven): logical slots {2lg, 2lg+1}, phys = ^(lr&7).
    const int s0 = ((2 * lg) ^ (lr & 7)) * 16;
    const int s1 = ((2 * lg + 1) ^ (lr & 7)) * 16;
    int arow[4], brow[4];
    #pragma unroll
    for (int m = 0; m < 4; ++m) {
        arow[m] = (wr * 64 + m * 16 + lr) * 128;
        brow[m] = (wc * 64 + m * 16 + lr) * 128;
    }

    f32x4 acc[4][4] = {};
    float rs[4][4];
    #pragma unroll
    for (int m = 0; m < 4; ++m)
        #pragma unroll
        for (int j = 0; j < 4; ++j) rs[m][j] = 0.f;

    #define STAGE(gsrc, dstbase) do {                                               \
        _Pragma("unroll")                                                           \
        for (int q = 0; q < 4; ++q)                                                 \
            __builtin_amdgcn_global_load_lds(                                       \
                (const AS1 void*)((gsrc) + srcOff[q]),                              \
                (AS3 void*)(lds + (dstbase) + q * 4096 + tid * 16), 16, 0, 0);      \
    } while (0)

    #define LDF(dst, base_) do {                                                    \
        i32x4 lo_ = *(const i32x4*)((base_) + s0);                                  \
        i32x4 hi_ = *(const i32x4*)((base_) + s1);                                  \
        dst = __builtin_shufflevector(lo_, hi_, 0, 1, 2, 3, 4, 5, 6, 7);            \
    } while (0)

    // rowsum flush for panel (P, BY); resets rs. 16 predicated atomic issues.
    #define FLUSH_RS(P, BY) do {                                                    \
        _Pragma("unroll")                                                           \
        for (int m = 0; m < 4; ++m)                                                 \
            _Pragma("unroll")                                                       \
            for (int j = 0; j < 4; ++j) {                                           \
                float v = rs[m][j];                                                 \
                v += __shfl_xor(v, 1);                                              \
                v += __shfl_xor(v, 2);                                              \
                v += __shfl_xor(v, 4);                                              \
                v += __shfl_xor(v, 8);                                              \
                if (lr == 0)                                                        \
                    atomicAdd(&rowsum[(P) * NB + (BY) * 128 + wr * 64 + m * 16 + lg * 4 + j], v); \
                rs[m][j] = 0.f;                                                     \
            }                                                                       \
    } while (0)

    #define SC 0x7F7F7F7F
    constexpr float C10 = 14.42695040888963f;

    // prologue: stages 0,1 (unit 0, k=0,1); drain stage 0 only (8 newer)
    {
        UnitInfo u0 = unit_info(nrm8, base);
        STAGE(u0.Ag, 0);
        STAGE(u0.Bg, 32768);
        STAGE(u0.Ag + 128, 16384);
        STAGE(u0.Bg + 128, 32768 + 16384);
    }
    asm volatile("s_waitcnt vmcnt(8)" ::: "memory");
    __builtin_amdgcn_s_barrier();

    #pragma unroll 1
    for (int s = 0; s < 24; ++s) {
        const int u = s >> 2, k = s & 3;
        const int pb = s & 1;
        const UnitInfo cur = unit_info(nrm8, base + u);

        // fragments for stage s (into regs)
        const char* ab = lds + pb * 16384;
        const char* bb = lds + 32768 + pb * 16384;
        i32x8 af[4], bf[4];
        #pragma unroll
        for (int m = 0; m < 4; ++m) LDF(af[m], ab + arow[m]);
        #pragma unroll
        for (int n = 0; n < 4; ++n) LDF(bf[n], bb + brow[n]);

        // buf[pb] is dead once ALL waves' reads are done -> reuse for stage s+2
        if (s < 22) {
            asm volatile("s_waitcnt lgkmcnt(0)" ::: "memory");
            __builtin_amdgcn_s_barrier();
            const int s2 = s + 2;
            const UnitInfo nx = unit_info(nrm8, base + (s2 >> 2));
            STAGE(nx.Ag + (s2 & 3) * 128, pb * 16384);
            STAGE(nx.Bg + (s2 & 3) * 128, 32768 + pb * 16384);
        }

        __builtin_amdgcn_s_setprio(1);
        #pragma unroll
        for (int m = 0; m < 4; ++m)
            #pragma unroll
            for (int n = 0; n < 4; ++n)
                acc[m][n] = __builtin_amdgcn_mfma_scale_f32_16x16x128_f8f6f4(
                    af[m], bf[n], acc[m][n], 0, 0, 0, SC, 0, SC);
        __builtin_amdgcn_s_setprio(0);

        // per-unit epilogue (k==3): overlaps the in-flight DMA
        bool flush = false;
        if (k == 3) {
            if (cur.by == cur.bx && wr == wc) {
                #pragma unroll
                for (int m = 0; m < 4; ++m)
                    #pragma unroll
                    for (int j = 0; j < 4; ++j)
                        if (lr == lg * 4 + j)
                            diag[cur.p * NB + cur.by * 128 + wr * 64 + m * 16 + lr] = acc[m][m][j];
            }
            float cs[4] = {0.f, 0.f, 0.f, 0.f};
            #pragma unroll
            for (int m = 0; m < 4; ++m)
                #pragma unroll
                for (int n = 0; n < 4; ++n)
                    #pragma unroll
                    for (int j = 0; j < 4; ++j) {
                        float e = fexp2(fmaf(acc[m][n][j], C10, -C10));
                        rs[m][j] += e;
                        cs[n] += e;
                    }
            #pragma unroll
            for (int n = 0; n < 4; ++n) {
                float v = cs[n];
                v += __shfl_xor(v, 16);
                v += __shfl_xor(v, 32);
                if (lg == 0)
                    atomicAdd(&colsum[cur.p * NB + cur.bx * 128 + wc * 64 + n * 16 + lr], v);
            }
            // panel (p,by) changes after this unit? flush rowsum partials now.
            flush = (u < 5) && (((base + u + 1) >> 5) != ((base + u) >> 5));
            if (flush) FLUSH_RS(cur.p, cur.by);
            #pragma unroll
            for (int m = 0; m < 4; ++m)
                #pragma unroll
                for (int n = 0; n < 4; ++n)
                    acc[m][n] = (f32x4){0.f, 0.f, 0.f, 0.f};
        }

        // gate: stage s+1 landed; stage s+2's 8 loads stay in flight.
        // newer-than-s+1 ops: 8 DMA (+4 colsum at k==3, +16 rowsum on flush;
        // diag stores only cause harmless over-drain).
        if (s < 22) {
            if (flush)       asm volatile("s_waitcnt vmcnt(28)" ::: "memory");
            else if (k == 3) asm volatile("s_waitcnt vmcnt(12)" ::: "memory");
            else             asm volatile("s_waitcnt vmcnt(8)" ::: "memory");
            __builtin_amdgcn_s_barrier();
        } else if (s == 22) {
            asm volatile("s_waitcnt vmcnt(0)" ::: "memory");
            __builtin_amdgcn_s_barrier();
        }
    }
    #undef STAGE
    #undef LDF

    // ---- final rowsum flush (last panel of this block) ----
    {
        const UnitInfo last = unit_info(nrm8, base + 5);
        FLUSH_RS(last.p, last.by);
    }
    #undef FLUSH_RS
}

// ---------------- final reduce: 48 blocks, atomic accumulate ----------------
__global__ __launch_bounds__(256) void finalize_kernel(
    const float* __restrict__ rowsum, const float* __restrict__ colsum,
    const float* __restrict__ diag, float* __restrict__ out)
{
    const int i = blockIdx.x * 256 + threadIdx.x;   // 48*256 = 12288 exactly
    float s = 0.5f * (logf(rowsum[i]) + logf(colsum[i])) + 10.0f - 10.0f * diag[i];
    #pragma unroll
    for (int m = 32; m >= 1; m >>= 1) s += __shfl_xor(s, m);
    __shared__ float sw[4];
    if ((threadIdx.x & 63) == 0) sw[threadIdx.x >> 6] = s;
    __syncthreads();
    if (threadIdx.x == 0)
        atomicAdd(out, (sw[0] + sw[1] + sw[2] + sw[3]) * (1.0f / (3.0f * NB)));
}

extern "C" void kernel_launch(void* const* d_in, const int* in_sizes, int n_in,
                              void* d_out, int out_size, void* d_ws, size_t ws_size,
                              hipStream_t stream) {
    const float* z0 = (const float*)d_in[0];
    const float* z1 = (const float*)d_in[1];
    const float* z2 = (const float*)d_in[2];
    float* out = (float*)d_out;

    char* ws = (char*)d_ws;
    unsigned char* nrm8 = (unsigned char*)ws;               // 3*4096*512 fp8 = 6.3 MB
    const size_t nrm_bytes = (size_t)3 * NB * ND;
    float* rowsum = (float*)(ws + nrm_bytes);               // 3*4096 f32
    float* colsum = rowsum + 3 * NB;                        // 3*4096 f32
    float* diag = colsum + 3 * NB;                          // 3*4096 f32 (fully overwritten)

    hipMemsetAsync(out, 0, sizeof(float), stream);
    nrm_kernel<<<dim3(NB / 4, 3), 256, 0, stream>>>(z0, z1, z2, nrm8, rowsum, colsum);
    pair_gemm_kernel<<<512, 256, 0, stream>>>(nrm8, rowsum, colsum, diag);
    finalize_kernel<<<48, 256, 0, stream>>>(rowsum, colsum, diag, out);
}

// Round 21
// 57.758 us; speedup vs baseline: 1.5878x; 1.0398x over previous
//
#include <hip/hip_runtime.h>
#include <hip/hip_bf16.h>

#define NB 4096
#define ND 512

typedef int i32x4 __attribute__((ext_vector_type(4)));
typedef int i32x8 __attribute__((ext_vector_type(8)));
typedef float f32x4 __attribute__((ext_vector_type(4)));

#define AS1 __attribute__((address_space(1)))
#define AS3 __attribute__((address_space(3)))

// raw v_exp_f32: D = 2^S0 (pure ALU, register-dep ordered)
__device__ __forceinline__ float fexp2(float x) {
    float r;
    asm("v_exp_f32 %0, %1" : "=v"(r) : "v"(x));
    return r;
}

// ---- f32 -> fp8 e4m3fn (OCP), RNE, |x| <= 1 ----
__device__ __forceinline__ unsigned int f2e4m3(float x) {
    float a = fabsf(x);
    unsigned s = (__float_as_uint(x) >> 24) & 0x80u;
    if (a < 0.015625f) {                       // denorm/zero: step 2^-9
        int q = __float2int_rn(a * 512.0f);
        return s | (unsigned)q;
    }
    unsigned u = __float_as_uint(a);
    u += 0x7FFFFu + ((u >> 20) & 1u);          // RNE to 3-bit mantissa
    unsigned e8 = (u >> 23) - 120u;
    unsigned m = (u >> 20) & 7u;
    return s | (e8 << 3) | m;
}

// ---------------- normalize + cast to fp8 (wave per row) + zero-init sums ----------------
__global__ __launch_bounds__(256) void nrm_kernel(
    const float* __restrict__ z0, const float* __restrict__ z1,
    const float* __restrict__ z2, unsigned char* __restrict__ nrm8,
    float* __restrict__ rowsum, float* __restrict__ colsum)
{
    const int w = threadIdx.x >> 6, lane = threadIdx.x & 63;
    const int row = blockIdx.x * 4 + w;
    const int p = blockIdx.y;
    if (lane == 0) {
        rowsum[p * NB + row] = 0.f;
        colsum[p * NB + row] = 0.f;
    }
    const float* z = (p == 0) ? z0 : (p == 1) ? z1 : z2;
    const float4* zr = (const float4*)(z + (size_t)row * ND);
    const float4 a = zr[lane * 2], b = zr[lane * 2 + 1];
    float ss = a.x * a.x + a.y * a.y + a.z * a.z + a.w * a.w
             + b.x * b.x + b.y * b.y + b.z * b.z + b.w * b.w;
    #pragma unroll
    for (int m = 32; m >= 1; m >>= 1) ss += __shfl_xor(ss, m);
    const float inv = 1.0f / fmaxf(sqrtf(ss), 1e-8f);
    uint2 o;
    o.x = f2e4m3(a.x * inv) | (f2e4m3(a.y * inv) << 8)
        | (f2e4m3(a.z * inv) << 16) | (f2e4m3(a.w * inv) << 24);
    o.y = f2e4m3(b.x * inv) | (f2e4m3(b.y * inv) << 8)
        | (f2e4m3(b.z * inv) << 16) | (f2e4m3(b.w * inv) << 24);
    *(uint2*)(nrm8 + ((size_t)p * NB + row) * ND + lane * 8) = o;
}

// ---------------- fused pair GEMM, MX-fp8: 48 KB LDS, 3 blocks/CU ----------------
// 768 blocks x 4 bx-units (16 stages), all co-resident (3/CU), tail-free.
// (p, by) is BLOCK-INVARIANT -> A uses a single 16 KB buffer, re-staged per
// k-stage after the mid-stage lgkm(0)+barrier (all waves' A reads are in
// regs by then). B keeps the proven 2-buffer 2-deep rotation. Gates:
// vmcnt(4) normal / vmcnt(8) at k==3 / vmcnt(0) at s==14. Rowsum flushes
// once post-loop (panel never changes mid-block).
__global__ __launch_bounds__(256, 3) void pair_gemm_kernel(
    const unsigned char* __restrict__ nrm8,
    float* __restrict__ rowsum, float* __restrict__ colsum,
    float* __restrict__ diag)
{
    const int bid = blockIdx.x;                       // 768 blocks
    const int base = (bid & 7) * 384 + (bid >> 3) * 4;  // first unit (XCD-chunked)
    const int p = base >> 10;
    const int rem = base & 1023;
    const int by = rem >> 5;                          // block-invariant
    const int bx0 = rem & 31;                         // units bx0..bx0+3 (<=31)
    const int ia = (p == 2) ? 1 : 0;
    const int ib = (p == 0) ? 1 : 2;

    const char* Ag = (const char*)nrm8 + ((size_t)ia * NB + (size_t)by * 128) * ND;
    const char* Bg = (const char*)nrm8 + ((size_t)ib * NB + (size_t)bx0 * 128) * ND;
    // B unit stride = 128 * ND = 65536 bytes

    __shared__ char lds[49152];  // A buf at 0 (16KB); B bufs at 16384, 32768

    const int tid = threadIdx.x;
    const int lane = tid & 63;
    const int w = tid >> 6;
    const int wr = w >> 1, wc = w & 1;   // 2x2 wave grid; wave tile 64x64
    const int lr = lane & 15, lg = lane >> 4;

    // staging map (proven): chunk c = q*256+tid -> LDS linear c*16; source row
    // rr = c>>3, phys slot qp = c&7 holds logical qp^(rr&7) (rule 21).
    int srcOff[4];
    #pragma unroll
    for (int q = 0; q < 4; ++q) {
        const int c = q * 256 + tid;
        const int rr = c >> 3;
        srcOff[q] = rr * ND + (((c & 7) ^ (rr & 7)) * 16);
    }

    // frag reads (proven): logical slots {2lg, 2lg+1}, phys = ^(lr&7).
    const int s0 = ((2 * lg) ^ (lr & 7)) * 16;
    const int s1 = ((2 * lg + 1) ^ (lr & 7)) * 16;
    int arow[4], brow[4];
    #pragma unroll
    for (int m = 0; m < 4; ++m) {
        arow[m] = (wr * 64 + m * 16 + lr) * 128;
        brow[m] = (wc * 64 + m * 16 + lr) * 128;
    }

    f32x4 acc[4][4] = {};
    float rs[4][4];
    #pragma unroll
    for (int m = 0; m < 4; ++m)
        #pragma unroll
        for (int j = 0; j < 4; ++j) rs[m][j] = 0.f;

    #define STAGE(gsrc, dstbase) do {                                               \
        _Pragma("unroll")                                                           \
        for (int q = 0; q < 4; ++q)                                                 \
            __builtin_amdgcn_global_load_lds(                                       \
                (const AS1 void*)((gsrc) + srcOff[q]),                              \
                (AS3 void*)(lds + (dstbase) + q * 4096 + tid * 16), 16, 0, 0);      \
    } while (0)

    #define LDF(dst, base_) do {                                                    \
        i32x4 lo_ = *(const i32x4*)((base_) + s0);                                  \
        i32x4 hi_ = *(const i32x4*)((base_) + s1);                                  \
        dst = __builtin_shufflevector(lo_, hi_, 0, 1, 2, 3, 4, 5, 6, 7);            \
    } while (0)

    #define SC 0x7F7F7F7F
    constexpr float C10 = 14.42695040888963f;

    // prologue: A(0)->Abuf, B(0)->Bbuf0, B(1)->Bbuf1; drain A(0)+B(0)
    STAGE(Ag, 0);
    STAGE(Bg, 16384);
    STAGE(Bg + 128, 32768);
    asm volatile("s_waitcnt vmcnt(4)" ::: "memory");
    __builtin_amdgcn_s_barrier();

    #pragma unroll 1
    for (int s = 0; s < 16; ++s) {
        const int u = s >> 2, k = s & 3;
        const int pb = s & 1;

        // fragments for stage s (into regs)
        const char* bb = lds + 16384 + pb * 16384;
        i32x8 af[4], bf[4];
        #pragma unroll
        for (int m = 0; m < 4; ++m) LDF(af[m], lds + arow[m]);
        #pragma unroll
        for (int n = 0; n < 4; ++n) LDF(bf[n], bb + brow[n]);

        // mid-stage: all waves' reads in regs -> re-stage A into the single
        // buffer and B(s+2) into the just-read B buffer.
        if (s < 15) {
            asm volatile("s_waitcnt lgkmcnt(0)" ::: "memory");
            __builtin_amdgcn_s_barrier();
            STAGE(Ag + ((s + 1) & 3) * 128, 0);
            if (s < 14) {
                const int s2 = s + 2;
                STAGE(Bg + (size_t)(s2 >> 2) * 65536 + (s2 & 3) * 128,
                      16384 + pb * 16384);
            }
        }

        __builtin_amdgcn_s_setprio(1);
        #pragma unroll
        for (int m = 0; m < 4; ++m)
            #pragma unroll
            for (int n = 0; n < 4; ++n)
                acc[m][n] = __builtin_amdgcn_mfma_scale_f32_16x16x128_f8f6f4(
                    af[m], bf[n], acc[m][n], 0, 0, 0, SC, 0, SC);
        __builtin_amdgcn_s_setprio(0);

        // per-unit epilogue (k==3): overlaps the in-flight DMA
        if (k == 3) {
            const int bxg = bx0 + u;
            if (by == bxg && wr == wc) {
                #pragma unroll
                for (int m = 0; m < 4; ++m)
                    #pragma unroll
                    for (int j = 0; j < 4; ++j)
                        if (lr == lg * 4 + j)
                            diag[p * NB + by * 128 + wr * 64 + m * 16 + lr] = acc[m][m][j];
            }
            float cs[4] = {0.f, 0.f, 0.f, 0.f};
            #pragma unroll
            for (int m = 0; m < 4; ++m)
                #pragma unroll
                for (int n = 0; n < 4; ++n)
                    #pragma unroll
                    for (int j = 0; j < 4; ++j) {
                        float e = fexp2(fmaf(acc[m][n][j], C10, -C10));
                        rs[m][j] += e;
                        cs[n] += e;
                    }
            #pragma unroll
            for (int n = 0; n < 4; ++n) {
                float v = cs[n];
                v += __shfl_xor(v, 16);
                v += __shfl_xor(v, 32);
                if (lg == 0)
                    atomicAdd(&colsum[p * NB + bxg * 128 + wc * 64 + n * 16 + lr], v);
            }
            #pragma unroll
            for (int m = 0; m < 4; ++m)
                #pragma unroll
                for (int n = 0; n < 4; ++n)
                    acc[m][n] = (f32x4){0.f, 0.f, 0.f, 0.f};
        }

        // gate: drain A(s+1)+B(s+1); leave B(s+2) (4 newest) in flight.
        // k==3: +4 colsum atomics newest -> vmcnt(8) (diag stores over-drain
        // harmlessly on the few by==bx waves).
        if (s < 14) {
            if (k == 3) asm volatile("s_waitcnt vmcnt(8)" ::: "memory");
            else        asm volatile("s_waitcnt vmcnt(4)" ::: "memory");
            __builtin_amdgcn_s_barrier();
        } else if (s == 14) {
            asm volatile("s_waitcnt vmcnt(0)" ::: "memory");
            __builtin_amdgcn_s_barrier();
        }
    }
    #undef STAGE
    #undef LDF

    // ---- final rowsum flush (single panel per block) ----
    #pragma unroll
    for (int m = 0; m < 4; ++m)
        #pragma unroll
        for (int j = 0; j < 4; ++j) {
            float v = rs[m][j];
            v += __shfl_xor(v, 1);
            v += __shfl_xor(v, 2);
            v += __shfl_xor(v, 4);
            v += __shfl_xor(v, 8);
            if (lr == 0)
                atomicAdd(&rowsum[p * NB + by * 128 + wr * 64 + m * 16 + lg * 4 + j], v);
        }
}

// ---------------- final reduce: 48 blocks, atomic accumulate ----------------
__global__ __launch_bounds__(256) void finalize_kernel(
    const float* __restrict__ rowsum, const float* __restrict__ colsum,
    const float* __restrict__ diag, float* __restrict__ out)
{
    const int i = blockIdx.x * 256 + threadIdx.x;   // 48*256 = 12288 exactly
    float s = 0.5f * (logf(rowsum[i]) + logf(colsum[i])) + 10.0f - 10.0f * diag[i];
    #pragma unroll
    for (int m = 32; m >= 1; m >>= 1) s += __shfl_xor(s, m);
    __shared__ float sw[4];
    if ((threadIdx.x & 63) == 0) sw[threadIdx.x >> 6] = s;
    __syncthreads();
    if (threadIdx.x == 0)
        atomicAdd(out, (sw[0] + sw[1] + sw[2] + sw[3]) * (1.0f / (3.0f * NB)));
}

extern "C" void kernel_launch(void* const* d_in, const int* in_sizes, int n_in,
                              void* d_out, int out_size, void* d_ws, size_t ws_size,
                              hipStream_t stream) {
    const float* z0 = (const float*)d_in[0];
    const float* z1 = (const float*)d_in[1];
    const float* z2 = (const float*)d_in[2];
    float* out = (float*)d_out;

    char* ws = (char*)d_ws;
    unsigned char* nrm8 = (unsigned char*)ws;               // 3*4096*512 fp8 = 6.3 MB
    const size_t nrm_bytes = (size_t)3 * NB * ND;
    float* rowsum = (float*)(ws + nrm_bytes);               // 3*4096 f32
    float* colsum = rowsum + 3 * NB;                        // 3*4096 f32
    float* diag = colsum + 3 * NB;                          // 3*4096 f32 (fully overwritten)

    hipMemsetAsync(out, 0, sizeof(float), stream);
    nrm_kernel<<<dim3(NB / 4, 3), 256, 0, stream>>>(z0, z1, z2, nrm8, rowsum, colsum);
    pair_gemm_kernel<<<768, 256, 0, stream>>>(nrm8, rowsum, colsum, diag);
    finalize_kernel<<<48, 256, 0, stream>>>(rowsum, colsum, diag, out);
}